// Round 8
// baseline (416.467 us; speedup 1.0000x reference)
//
#include <hip/hip_runtime.h>
#include <hip/hip_bf16.h>
#include <cstdint>

typedef __attribute__((ext_vector_type(4))) float f32x4;
typedef _Float16 f16x8 __attribute__((ext_vector_type(8)));

#define BN_EPS 1e-5f

// ---------------- fp32 -> fp16 cast (vectorized, 8 elems/thread) ----------------
__global__ __launch_bounds__(256)
void cast_f32_f16(const float* __restrict__ src, _Float16* __restrict__ dst, int n8) {
    int i = blockIdx.x * blockDim.x + threadIdx.x;
    if (i >= n8) return;
    const float4* s4 = (const float4*)src;
    float4 a = s4[2 * (size_t)i];
    float4 b = s4[2 * (size_t)i + 1];
    f16x8 h;
    h[0] = (_Float16)a.x; h[1] = (_Float16)a.y; h[2] = (_Float16)a.z; h[3] = (_Float16)a.w;
    h[4] = (_Float16)b.x; h[5] = (_Float16)b.y; h[6] = (_Float16)b.z; h[7] = (_Float16)b.w;
    *(f16x8*)(dst + 8 * (size_t)i) = h;
}

// async global->LDS, 16B per lane, wave-uniform LDS base
__device__ __forceinline__ void async16(const char* g, _Float16* l) {
    __builtin_amdgcn_global_load_lds(
        (const __attribute__((address_space(1))) unsigned int*)(uintptr_t)g,
        (__attribute__((address_space(3))) unsigned int*)(uintptr_t)l,
        16, 0, 0);
}

// ================= m97-structure GEMM: 128x128 tile, BK=32, SINGLE buffer =================
// 4 waves (2x2), 64x64 out per wave. LDS = A 8KB + B 8KB + red 8KB = 24KB -> 4 blocks/CU
// (VGPR-capped at 4 waves/SIMD). Per K-tile: sync; stage (4x global_load_lds w=16); sync
// (compiler emits vmcnt(0) drain at __syncthreads); ds_read_b128 frags; 16 MFMA.
// Overlap comes from 4 independent blocks/CU decorrelating stage/read/MFMA phases (m114),
// NOT from in-wave pipelining (m97: 874-912 TF verified on this chip).
// Read swizzle (verified 0-conflict r3/r7): byte ^= ((byte>>7)&3)<<4 on [128][32]f16 (64B
// rows); staging keeps LDS linear and pre-permutes the global 16B k-slot per lane.

__global__ __launch_bounds__(256)
void gemm_gbn_kernel(const _Float16* __restrict__ A,
                     const _Float16* __restrict__ Bw,
                     const float* __restrict__ priors,
                     const float* __restrict__ gamma,
                     const float* __restrict__ beta,
                     float* __restrict__ Z,
                     int M, int N, int K)
{
    __shared__ __align__(16) _Float16 As[128 * 32];   // 8 KB
    __shared__ __align__(16) _Float16 Bs[128 * 32];   // 8 KB
    __shared__ float red[2][128][2];                  // 8 KB

    const int tid  = threadIdx.x;
    const int lane = tid & 63;
    const int wid  = tid >> 6;     // 0..3
    const int wr   = wid >> 1;     // 0..1 (64-row slice)
    const int wc   = wid & 1;      // 0..1 (64-col slice)
    const int fr   = lane & 15;
    const int kg   = lane >> 4;

    // XCD-aware bijective swizzle: 2048 blocks -> 8 chunks of 256; col-block fastest within
    // a chunk so the 8 col-blocks of one row-panel run on the same XCD (A-panel L2-shared).
    const int bid = blockIdx.x;
    const int swz = (bid & 7) * 256 + (bid >> 3);
    const int row0 = (swz >> 3) * 128;
    const int col0 = (swz & 7) * 128;

    // staging sources: thread t covers row t>>2 (+64 on 2nd call); pre-permuted 16B k-slot
    const int sperm = ((tid & 3) ^ ((tid >> 3) & 3)) * 16;
    const char* a0 = (const char*)A  + (size_t)(row0 + (tid >> 2)) * (size_t)K * 2 + sperm;
    const char* a1 = a0 + (size_t)64 * K * 2;
    const char* b0 = (const char*)Bw + (size_t)(col0 + (tid >> 2)) * (size_t)K * 2 + sperm;
    const char* b1 = b0 + (size_t)64 * K * 2;

    // fragment byte offsets ([128][32] f16, 64B rows), swizzled (0-conflict verified)
    int aoff = (wr * 64 + fr) * 64 + kg * 16;
    aoff ^= ((aoff >> 7) & 3) << 4;
    int boff = (wc * 64 + fr) * 64 + kg * 16;
    boff ^= ((boff >> 7) & 3) << 4;

    f32x4 acc[4][4];
    #pragma unroll
    for (int m = 0; m < 4; ++m)
        #pragma unroll
        for (int n = 0; n < 4; ++n)
            acc[m][n] = (f32x4)0.0f;

    const int nt = K >> 5;                 // 64 K-tiles
    for (int kt = 0; kt < nt; ++kt) {
        __syncthreads();                   // previous tile fully consumed
        async16(a0 + (size_t)kt * 64, As + wid * 512);
        async16(a1 + (size_t)kt * 64, As + 2048 + wid * 512);
        async16(b0 + (size_t)kt * 64, Bs + wid * 512);
        async16(b1 + (size_t)kt * 64, Bs + 2048 + wid * 512);
        __syncthreads();                   // drains vmcnt -> staged tile visible

        f16x8 a[4], b[4];
        #pragma unroll
        for (int n = 0; n < 4; ++n) b[n] = *(const f16x8*)((const char*)Bs + boff + n * 1024);
        #pragma unroll
        for (int m = 0; m < 4; ++m) a[m] = *(const f16x8*)((const char*)As + aoff + m * 1024);

        #pragma unroll
        for (int m = 0; m < 4; ++m)
            #pragma unroll
            for (int n = 0; n < 4; ++n)
                acc[m][n] = __builtin_amdgcn_mfma_f32_16x16x32_f16(a[m], b[n], acc[m][n], 0, 0, 0);
    }

    // ---- fused Ghost BatchNorm + priors epilogue (block = one 128-row virtual batch) ----
    #pragma unroll
    for (int n = 0; n < 4; ++n) {
        float s1 = 0.f, s2 = 0.f;
        #pragma unroll
        for (int m = 0; m < 4; ++m)
            #pragma unroll
            for (int j = 0; j < 4; ++j) {
                float v = acc[m][n][j];
                s1 += v; s2 += v * v;
            }
        s1 += __shfl_xor(s1, 16); s2 += __shfl_xor(s2, 16);
        s1 += __shfl_xor(s1, 32); s2 += __shfl_xor(s2, 32);
        if (lane < 16) {
            red[wr][wc * 64 + n * 16 + lane][0] = s1;
            red[wr][wc * 64 + n * 16 + lane][1] = s2;
        }
    }
    __syncthreads();

    const int rowb = row0 + wr * 64 + kg * 4;
    #pragma unroll
    for (int n = 0; n < 4; ++n) {
        const int c = wc * 64 + n * 16 + fr;
        float s1 = red[0][c][0] + red[1][c][0];
        float s2 = red[0][c][1] + red[1][c][1];
        float mean = s1 * (1.f / 128.f);
        float var  = s2 * (1.f / 128.f) - mean * mean;
        float rstd = rsqrtf(var + BN_EPS);
        float g = gamma[col0 + c] * rstd;
        float b = beta[col0 + c] - mean * g;
        #pragma unroll
        for (int m = 0; m < 4; ++m)
            #pragma unroll
            for (int j = 0; j < 4; ++j) {
                int r = rowb + m * 16 + j;
                size_t off = (size_t)r * N + col0 + c;
                Z[off] = (acc[m][n][j] * g + b) * priors[off];
            }
    }
}

// ---------------- sparsemax: one wave per row of 1024, exact Michelot projection ----------------
__device__ __forceinline__ float waveSum(float v) {
    #pragma unroll
    for (int off = 32; off > 0; off >>= 1) v += __shfl_xor(v, off);
    return v;
}

__global__ __launch_bounds__(256)
void sparsemax_kernel(float* __restrict__ Z) {
    const int lane = threadIdx.x & 63;
    const int wid  = threadIdx.x >> 6;
    const size_t row = (size_t)blockIdx.x * 4 + wid;
    float4* zr4 = (float4*)(Z + row * 1024);

    float p[16];
    #pragma unroll
    for (int j = 0; j < 4; ++j) {
        float4 t = zr4[lane * 4 + j];
        p[4 * j + 0] = t.x; p[4 * j + 1] = t.y; p[4 * j + 2] = t.z; p[4 * j + 3] = t.w;
    }

    float s = 0.f;
    #pragma unroll
    for (int i = 0; i < 16; ++i) s += p[i];
    s = waveSum(s);

    float kc  = 1024.f;
    float tau = (s - 1.f) * (1.f / 1024.f);
    for (int it = 0; it < 64; ++it) {
        float s2 = 0.f, c2 = 0.f;
        #pragma unroll
        for (int i = 0; i < 16; ++i) {
            if (p[i] > tau) { s2 += p[i]; c2 += 1.f; }
        }
        s2 = waveSum(s2); c2 = waveSum(c2);
        if (c2 == kc) break;        // support stable -> tau exact
        kc = c2;
        tau = (s2 - 1.f) / c2;
    }

    #pragma unroll
    for (int j = 0; j < 4; ++j) {
        float4 o;
        o.x = fmaxf(p[4 * j + 0] - tau, 0.f);
        o.y = fmaxf(p[4 * j + 1] - tau, 0.f);
        o.z = fmaxf(p[4 * j + 2] - tau, 0.f);
        o.w = fmaxf(p[4 * j + 3] - tau, 0.f);
        zr4[lane * 4 + j] = o;
    }
}

extern "C" void kernel_launch(void* const* d_in, const int* in_sizes, int n_in,
                              void* d_out, int out_size, void* d_ws, size_t ws_size,
                              hipStream_t stream)
{
    const float* priors = (const float*)d_in[0];
    const float* feat   = (const float*)d_in[1];
    const float* W      = (const float*)d_in[2];
    const float* gamma  = (const float*)d_in[3];
    const float* beta   = (const float*)d_in[4];
    float* out = (float*)d_out;

    const int Nf = in_sizes[3];              // 1024
    const int Kf = in_sizes[2] / Nf;         // 2048
    const int Mr = in_sizes[1] / Kf;         // 32768

    _Float16* Ah = (_Float16*)d_ws;                                  // M*K*2 = 128 MB
    _Float16* Wh = (_Float16*)((char*)d_ws + (size_t)Mr * Kf * 2);   // N*K*2 =   4 MB

    {
        int n8 = Mr * (Kf / 8);
        cast_f32_f16<<<(n8 + 255) / 256, 256, 0, stream>>>(feat, Ah, n8);
    }
    {
        int n8 = Nf * (Kf / 8);
        cast_f32_f16<<<(n8 + 255) / 256, 256, 0, stream>>>(W, Wh, n8);
    }

    int nblk = (Mr / 128) * (Nf / 128);      // 2048, divisible by 8
    gemm_gbn_kernel<<<nblk, 256, 0, stream>>>(Ah, Wh, priors, gamma, beta, out, Mr, Nf, Kf);

    sparsemax_kernel<<<Mr / 4, 256, 0, stream>>>(out);
}

// Round 9
// 342.092 us; speedup vs baseline: 1.2174x; 1.2174x over previous
//
#include <hip/hip_runtime.h>
#include <hip/hip_bf16.h>
#include <cstdint>

typedef __attribute__((ext_vector_type(4))) float f32x4;
typedef _Float16 f16x8 __attribute__((ext_vector_type(8)));

#define BN_EPS 1e-5f

// ---------------- fp32 -> fp16 cast (vectorized, 8 elems/thread) ----------------
__global__ __launch_bounds__(256)
void cast_f32_f16(const float* __restrict__ src, _Float16* __restrict__ dst, int n8) {
    int i = blockIdx.x * blockDim.x + threadIdx.x;
    if (i >= n8) return;
    const float4* s4 = (const float4*)src;
    float4 a = s4[2 * (size_t)i];
    float4 b = s4[2 * (size_t)i + 1];
    f16x8 h;
    h[0] = (_Float16)a.x; h[1] = (_Float16)a.y; h[2] = (_Float16)a.z; h[3] = (_Float16)a.w;
    h[4] = (_Float16)b.x; h[5] = (_Float16)b.y; h[6] = (_Float16)b.z; h[7] = (_Float16)b.w;
    *(f16x8*)(dst + 8 * (size_t)i) = h;
}

// async global->LDS, 16B per lane, wave-uniform LDS base
__device__ __forceinline__ void async16(const char* g, char* l) {
    __builtin_amdgcn_global_load_lds(
        (const __attribute__((address_space(1))) unsigned int*)(uintptr_t)g,
        (__attribute__((address_space(3))) unsigned int*)(uintptr_t)l,
        16, 0, 0);
}

// ============== 8-phase (m201-template) GEMM: 256x256, BK=64, k-split phases ==============
// 8 waves (2Mx4N), per-wave out 128x64 = acc[8][4]. LDS 128KB: {A,B} x {khalf 0,1} x
// {parity 0,1} x 16KB ([256][32] f16 half-tiles). Per K-tile t, 4 phases:
//   P1: read B@k0 (4xb128) + A(mh0)@k0 (4) | stage Ak0(t+1) | bar | lgkm0 | 16 MFMA | bar
//   P2: read A(mh1)@k0 (4)                 | stage Bk0(t+1) | bar | lgkm0 | 16 MFMA | vmcnt(4) | bar
//   P3: read B@k1 + A(mh0)@k1 (8)          | stage Ak1(t+1) | bar | lgkm0 | 16 MFMA | bar
//   P4: read A(mh1)@k1 (4)                 | stage Bk1(t+1) | bar | lgkm0 | 16 MFMA | vmcnt(4) | bar
// Ledger (2 loads/half-tile): at P2's vmcnt(4), outstanding = {Ak1(t),Bk1(t),Ak0(t+1),Bk0(t+1)}
// = 8 -> retires Ak1(t),Bk1(t), needed at P3(t). At P4's vmcnt(4): outstanding = 4 half-tiles of
// t+1 -> retires Ak0(t+1),Bk0(t+1), needed at P1(t+1). Never drains to 0 in steady state.
// Overwrite hazard: stage at P1(t) targets parity(t+1) == parity(t-1), whose last reads were
// drained by P2(t-1)'s lgkmcnt(0), >= 2 barriers earlier. Tail (t=nt-1): no stage; vmcnt(0)
// at P2 (retires Ak1,Bk1 of the last tile). Reads use the verified 0-conflict XOR swizzle.

#define LDSA(h, par) (lds + (h) * 32768 + (par) * 16384)
#define LDSB(h, par) (lds + 65536 + (h) * 32768 + (par) * 16384)

__device__ __forceinline__ void dsReadB(f16x8 (&b)[4], const char* bh, int boff) {
    #pragma unroll
    for (int n = 0; n < 4; ++n) b[n] = *(const f16x8*)(bh + boff + n * 1024);
}
template<int MH>
__device__ __forceinline__ void dsReadA(f16x8 (&a)[4], const char* ah, int aoff) {
    #pragma unroll
    for (int m = 0; m < 4; ++m) a[m] = *(const f16x8*)(ah + aoff + MH * 4096 + m * 1024);
}
template<int MH>
__device__ __forceinline__ void mfma16(const f16x8 (&a)[4], const f16x8 (&b)[4], f32x4 (&acc)[8][4]) {
    __builtin_amdgcn_s_setprio(1);
    #pragma unroll
    for (int m = 0; m < 4; ++m)
        #pragma unroll
        for (int n = 0; n < 4; ++n)
            acc[MH * 4 + m][n] = __builtin_amdgcn_mfma_f32_16x16x32_f16(a[m], b[n], acc[MH * 4 + m][n], 0, 0, 0);
    __builtin_amdgcn_s_setprio(0);
}

__global__ __launch_bounds__(512, 2)
void gemm_gbn_kernel(const _Float16* __restrict__ A,
                     const _Float16* __restrict__ Bw,
                     const float* __restrict__ priors,
                     const float* __restrict__ gamma,
                     const float* __restrict__ beta,
                     float* __restrict__ Z,
                     int M, int N, int K)
{
    __shared__ __align__(16) char lds[131072];

    const int tid  = threadIdx.x;
    const int lane = tid & 63;
    const int wid  = tid >> 6;     // 0..7
    const int wr   = wid >> 2;     // 0..1  (128-row half == one virtual batch)
    const int wc   = wid & 3;      // 0..3  (64-col slice)
    const int fr   = lane & 15;
    const int kg   = lane >> 4;

    // XCD-aware bijective swizzle (512 blocks, %8==0)
    const int bid = blockIdx.x;
    const int swz = (bid & 7) * 64 + (bid >> 3);
    const int row0 = (swz >> 2) * 256;
    const int col0 = (swz & 3) * 256;

    // staging sources: thread t covers row t>>2 (+128 on 2nd issue); pre-permuted 16B slot
    // within each 64B k-half row-segment: slot ^= (row>>1)&3 (matches the read swizzle).
    const int sperm = ((tid & 3) ^ ((tid >> 3) & 3)) * 16;
    const char* a0 = (const char*)A  + (size_t)(row0 + (tid >> 2)) * (size_t)K * 2 + sperm;
    const char* a1 = a0 + (size_t)128 * K * 2;
    const char* b0 = (const char*)Bw + (size_t)(col0 + (tid >> 2)) * (size_t)K * 2 + sperm;
    const char* b1 = b0 + (size_t)128 * K * 2;
    const int widB = wid * 1024;   // wave-uniform LDS byte base per 8KB issue

    // fragment byte offsets within a 16KB [256][32] f16 half-buffer, 0-conflict swizzled
    int aoff = (wr * 128 + fr) * 64 + kg * 16;
    aoff ^= ((aoff >> 7) & 3) << 4;
    int boff = (wc * 64 + fr) * 64 + kg * 16;
    boff ^= ((boff >> 7) & 3) << 4;

    f32x4 acc[8][4];
    #pragma unroll
    for (int m = 0; m < 8; ++m)
        #pragma unroll
        for (int n = 0; n < 4; ++n)
            acc[m][n] = (f32x4)0.0f;

    const int nt = K >> 6;   // 32 K-tiles of 64

    // prologue: stage tile 0 (Ak0, Bk0, Ak1, Bk1); land the k0 halves, keep k1 in flight
    {
        async16(a0, LDSA(0, 0) + widB);  async16(a1, LDSA(0, 0) + 8192 + widB);
        async16(b0, LDSB(0, 0) + widB);  async16(b1, LDSB(0, 0) + 8192 + widB);
        async16(a0 + 64, LDSA(1, 0) + widB);  async16(a1 + 64, LDSA(1, 0) + 8192 + widB);
        async16(b0 + 64, LDSB(1, 0) + widB);  async16(b1 + 64, LDSB(1, 0) + 8192 + widB);
    }
    asm volatile("s_waitcnt vmcnt(4)" ::: "memory");
    __builtin_amdgcn_s_barrier();

    for (int kt = 0; kt < nt; ++kt) {
        const int par = kt & 1, nxt = par ^ 1;
        const char* A0h = LDSA(0, par); const char* A1h = LDSA(1, par);
        const char* B0h = LDSB(0, par); const char* B1h = LDSB(1, par);
        const bool st = (kt + 1 < nt);
        const size_t cb = (size_t)(kt + 1) * 128;   // next tile's byte col-offset (k0)
        f16x8 a[4], b[4];

        // ---- P1: ks0, mh0 ----
        dsReadB(b, B0h, boff);
        dsReadA<0>(a, A0h, aoff);
        if (st) { async16(a0 + cb, LDSA(0, nxt) + widB); async16(a1 + cb, LDSA(0, nxt) + 8192 + widB); }
        __builtin_amdgcn_s_barrier();
        asm volatile("s_waitcnt lgkmcnt(0)" ::: "memory");
        mfma16<0>(a, b, acc);
        __builtin_amdgcn_s_barrier();

        // ---- P2: ks0, mh1 ----
        dsReadA<1>(a, A0h, aoff);
        if (st) { async16(b0 + cb, LDSB(0, nxt) + widB); async16(b1 + cb, LDSB(0, nxt) + 8192 + widB); }
        __builtin_amdgcn_s_barrier();
        asm volatile("s_waitcnt lgkmcnt(0)" ::: "memory");
        mfma16<1>(a, b, acc);
        if (st) { asm volatile("s_waitcnt vmcnt(4)" ::: "memory"); }
        else    { asm volatile("s_waitcnt vmcnt(0)" ::: "memory"); }
        __builtin_amdgcn_s_barrier();

        // ---- P3: ks1, mh0 ----
        dsReadB(b, B1h, boff);
        dsReadA<0>(a, A1h, aoff);
        if (st) { async16(a0 + cb + 64, LDSA(1, nxt) + widB); async16(a1 + cb + 64, LDSA(1, nxt) + 8192 + widB); }
        __builtin_amdgcn_s_barrier();
        asm volatile("s_waitcnt lgkmcnt(0)" ::: "memory");
        mfma16<0>(a, b, acc);
        __builtin_amdgcn_s_barrier();

        // ---- P4: ks1, mh1 ----
        dsReadA<1>(a, A1h, aoff);
        if (st) { async16(b0 + cb + 64, LDSB(1, nxt) + widB); async16(b1 + cb + 64, LDSB(1, nxt) + 8192 + widB); }
        __builtin_amdgcn_s_barrier();
        asm volatile("s_waitcnt lgkmcnt(0)" ::: "memory");
        mfma16<1>(a, b, acc);
        if (st) { asm volatile("s_waitcnt vmcnt(4)" ::: "memory"); }
        __builtin_amdgcn_s_barrier();
    }

    // ---- fused Ghost BatchNorm + priors epilogue (wave-local: wr half = one VBS) ----
    #pragma unroll
    for (int n = 0; n < 4; ++n) {
        float s1 = 0.f, s2 = 0.f;
        #pragma unroll
        for (int m = 0; m < 8; ++m)
            #pragma unroll
            for (int j = 0; j < 4; ++j) {
                float v = acc[m][n][j];
                s1 += v; s2 += v * v;
            }
        s1 += __shfl_xor(s1, 16); s2 += __shfl_xor(s2, 16);
        s1 += __shfl_xor(s1, 32); s2 += __shfl_xor(s2, 32);
        float mean = s1 * (1.f / 128.f);
        float var  = s2 * (1.f / 128.f) - mean * mean;
        float rstd = rsqrtf(var + BN_EPS);
        const int c = col0 + wc * 64 + n * 16 + fr;
        float g = gamma[c] * rstd;
        float b = beta[c] - mean * g;
        #pragma unroll
        for (int m = 0; m < 8; ++m)
            #pragma unroll
            for (int j = 0; j < 4; ++j) {
                int r = row0 + wr * 128 + m * 16 + kg * 4 + j;
                size_t off = (size_t)r * N + c;
                Z[off] = (acc[m][n][j] * g + b) * priors[off];
            }
    }
}

// ---------------- sparsemax: one wave per row of 1024, exact Michelot projection ----------------
__device__ __forceinline__ float waveSum(float v) {
    #pragma unroll
    for (int off = 32; off > 0; off >>= 1) v += __shfl_xor(v, off);
    return v;
}

__global__ __launch_bounds__(256)
void sparsemax_kernel(float* __restrict__ Z) {
    const int lane = threadIdx.x & 63;
    const int wid  = threadIdx.x >> 6;
    const size_t row = (size_t)blockIdx.x * 4 + wid;
    float4* zr4 = (float4*)(Z + row * 1024);

    float p[16];
    #pragma unroll
    for (int j = 0; j < 4; ++j) {
        float4 t = zr4[lane * 4 + j];
        p[4 * j + 0] = t.x; p[4 * j + 1] = t.y; p[4 * j + 2] = t.z; p[4 * j + 3] = t.w;
    }

    float s = 0.f;
    #pragma unroll
    for (int i = 0; i < 16; ++i) s += p[i];
    s = waveSum(s);

    float kc  = 1024.f;
    float tau = (s - 1.f) * (1.f / 1024.f);
    for (int it = 0; it < 64; ++it) {
        float s2 = 0.f, c2 = 0.f;
        #pragma unroll
        for (int i = 0; i < 16; ++i) {
            if (p[i] > tau) { s2 += p[i]; c2 += 1.f; }
        }
        s2 = waveSum(s2); c2 = waveSum(c2);
        if (c2 == kc) break;        // support stable -> tau exact
        kc = c2;
        tau = (s2 - 1.f) / c2;
    }

    #pragma unroll
    for (int j = 0; j < 4; ++j) {
        float4 o;
        o.x = fmaxf(p[4 * j + 0] - tau, 0.f);
        o.y = fmaxf(p[4 * j + 1] - tau, 0.f);
        o.z = fmaxf(p[4 * j + 2] - tau, 0.f);
        o.w = fmaxf(p[4 * j + 3] - tau, 0.f);
        zr4[lane * 4 + j] = o;
    }
}

extern "C" void kernel_launch(void* const* d_in, const int* in_sizes, int n_in,
                              void* d_out, int out_size, void* d_ws, size_t ws_size,
                              hipStream_t stream)
{
    const float* priors = (const float*)d_in[0];
    const float* feat   = (const float*)d_in[1];
    const float* W      = (const float*)d_in[2];
    const float* gamma  = (const float*)d_in[3];
    const float* beta   = (const float*)d_in[4];
    float* out = (float*)d_out;

    const int Nf = in_sizes[3];              // 1024
    const int Kf = in_sizes[2] / Nf;         // 2048
    const int Mr = in_sizes[1] / Kf;         // 32768

    _Float16* Ah = (_Float16*)d_ws;                                  // M*K*2 = 128 MB
    _Float16* Wh = (_Float16*)((char*)d_ws + (size_t)Mr * Kf * 2);   // N*K*2 =   4 MB

    {
        int n8 = Mr * (Kf / 8);
        cast_f32_f16<<<(n8 + 255) / 256, 256, 0, stream>>>(feat, Ah, n8);
    }
    {
        int n8 = Nf * (Kf / 8);
        cast_f32_f16<<<(n8 + 255) / 256, 256, 0, stream>>>(W, Wh, n8);
    }

    int nblk = (Mr / 256) * (Nf / 256);      // 512, divisible by 8
    gemm_gbn_kernel<<<nblk, 512, 0, stream>>>(Ah, Wh, priors, gamma, beta, out, Mr, Nf, Kf);

    sparsemax_kernel<<<Mr / 4, 256, 0, stream>>>(out);
}